// Round 1
// baseline (269.904 us; speedup 1.0000x reference)
//
#include <hip/hip_runtime.h>
#include <hip/hip_bf16.h>

#define FEATN 501
#define MLEN 1002
#define NB 8192
#define NT 512
#define DTC 0.01f

__device__ __forceinline__ float softplus_f(float x) {
    return fmaxf(x, 0.f) + log1pf(expf(-fabsf(x)));
}

// ---------------- Encoder kernel ----------------
// grid 256, block 256. Each block: 32 batches.
// Writes 26 coef floats per batch into coef[b*4096 + {0..25}] (the xi region,
// which the time kernel reads then overwrites).
__global__ __launch_bounds__(256) void enc_kernel(
    const float* __restrict__ E, const float* __restrict__ nu,
    const float* __restrict__ Bw1, const float* __restrict__ Bb1,
    const float* __restrict__ Bw2, const float* __restrict__ Bb2,
    const float* __restrict__ bw1, const float* __restrict__ bb1,
    const float* __restrict__ bw2, const float* __restrict__ bb2,
    float* coef) {
    __shared__ float m_lds[32][337];   // [batch][ii]  (chunk of 334, pad->337)
    __shared__ float hid[128][33];     // [h_row][batch]  rows 0..63 B-MLP, 64..127 beta-MLP
    __shared__ float nups[32], Eps[32];

    const int tid = threadIdx.x;
    const int blk = blockIdx.x;
    const int wave = tid >> 6, lane = tid & 63;

    // ---- phase 1: harmonic-mean reductions (8 batches per wave) ----
    for (int r = 0; r < 8; ++r) {
        const int bl = wave * 8 + r;
        const size_t base = (size_t)(blk * 32 + bl) * FEATN;
        float s1 = 0.f, s2 = 0.f;
        for (int i = lane; i < FEATN; i += 64) {
            float nv = nu[base + i];
            float Ev = E[base + i];
            float inv = 1.0f / nv;
            s1 += inv;
            s2 = fmaf(Ev, inv * inv, s2);
        }
        #pragma unroll
        for (int o = 32; o; o >>= 1) {
            s1 += __shfl_xor(s1, o);
            s2 += __shfl_xor(s2, o);
        }
        if (lane == 0) {
            float np = (float)FEATN / s1;
            nups[bl] = np;
            Eps[bl] = (s2 / (float)FEATN) * np * np;
        }
    }
    __syncthreads();

    // ---- phase 2: first-layer matvec, K-chunked (3 x 334) ----
    const int ht = tid >> 4;          // 0..15 : output-group of 8 h
    const int bt = tid & 15;          // 0..15 : batch pair
    const float* W1 = (ht < 8) ? Bw1 : bw1;
    const int hb = (ht & 7) * 8;

    float acc0[8] = {0.f, 0.f, 0.f, 0.f, 0.f, 0.f, 0.f, 0.f};
    float acc1[8] = {0.f, 0.f, 0.f, 0.f, 0.f, 0.f, 0.f, 0.f};

    for (int c = 0; c < 3; ++c) {
        const int i0 = c * 334;
        __syncthreads();
        for (int idx = tid; idx < 32 * 334; idx += 256) {
            const int bl = idx / 334;
            const int ii = idx - bl * 334;
            const int i = i0 + ii;
            const size_t bg = (size_t)(blk * 32 + bl);
            m_lds[bl][ii] = (i < FEATN) ? E[bg * FEATN + i]
                                        : nu[bg * FEATN + (i - FEATN)];
        }
        __syncthreads();

        #pragma unroll 2
        for (int ii = 0; ii < 334; ++ii) {
            const int i = i0 + ii;
            const float m0 = m_lds[bt * 2][ii];
            const float m1 = m_lds[bt * 2 + 1][ii];
            const float* wp = W1 + (size_t)i * 64 + hb;
            const float4 wA = *(const float4*)(wp);
            const float4 wB = *(const float4*)(wp + 4);
            acc0[0] = fmaf(m0, wA.x, acc0[0]); acc1[0] = fmaf(m1, wA.x, acc1[0]);
            acc0[1] = fmaf(m0, wA.y, acc0[1]); acc1[1] = fmaf(m1, wA.y, acc1[1]);
            acc0[2] = fmaf(m0, wA.z, acc0[2]); acc1[2] = fmaf(m1, wA.z, acc1[2]);
            acc0[3] = fmaf(m0, wA.w, acc0[3]); acc1[3] = fmaf(m1, wA.w, acc1[3]);
            acc0[4] = fmaf(m0, wB.x, acc0[4]); acc1[4] = fmaf(m1, wB.x, acc1[4]);
            acc0[5] = fmaf(m0, wB.y, acc0[5]); acc1[5] = fmaf(m1, wB.y, acc1[5]);
            acc0[6] = fmaf(m0, wB.z, acc0[6]); acc1[6] = fmaf(m1, wB.z, acc1[6]);
            acc0[7] = fmaf(m0, wB.w, acc0[7]); acc1[7] = fmaf(m1, wB.w, acc1[7]);
        }
    }

    // ---- bias + activation -> hid LDS ----
    {
        const float* b1 = (ht < 8) ? Bb1 : bb1;
        #pragma unroll
        for (int j = 0; j < 8; ++j) {
            const float bias = b1[hb + j];
            float v0 = acc0[j] + bias;
            float v1 = acc1[j] + bias;
            if (ht < 8) {
                v0 = fmaxf(v0, 0.f);
                v1 = fmaxf(v1, 0.f);
            } else {
                v0 = softplus_f(v0);
                v1 = softplus_f(v1);
            }
            hid[ht * 8 + j][bt * 2] = v0;
            hid[ht * 8 + j][bt * 2 + 1] = v1;
        }
    }
    __syncthreads();

    // ---- phase 3: second layer + coefficient write ----
    {
        const int bl = tid >> 3;     // 0..31
        const int k = tid & 7;       // 0..7
        float dB = 0.f, db = 0.f;
        #pragma unroll 8
        for (int h = 0; h < 64; ++h) {
            dB = fmaf(hid[h][bl],      Bw2[h * 8 + k], dB);
            db = fmaf(hid[64 + h][bl], bw2[h * 8 + k], db);
        }
        const float Bm = dB + Bb2[k];
        float be = softplus_f(db + bb2[k]);
        float Bs = Bm;
        Bs += __shfl_xor(Bs, 1);
        Bs += __shfl_xor(Bs, 2);
        Bs += __shfl_xor(Bs, 4);
        const float a = 1.f - DTC * be * (Bm + Bs);
        const float cc = DTC * be * Bm;
        const size_t bg = (size_t)(blk * 32 + bl);
        float* cb = coef + bg * 4096;
        cb[k] = a;
        cb[8 + k] = cc;
        cb[16 + k] = Bm;
        if (k == 0) {
            cb[24] = Bs * Eps[bl];
            cb[25] = nups[bl];
        }
    }
}

// ---------------- Time-loop kernel ----------------
// grid 2048, block 256: one wave per batch. lane = j*8+k (j: timestep in group
// of 8, k: internal-variable index).
__global__ __launch_bounds__(256) void time_kernel(
    const float* __restrict__ e, const float* __restrict__ ed,
    const float* coef, float* stress, float* xi_out) {
    const int wid = (blockIdx.x << 2) + (threadIdx.x >> 6);   // batch
    const int lane = threadIdx.x & 63;
    const int j = lane >> 3, k = lane & 7;

    const float* cb = coef + (size_t)wid * 4096;
    const float a = cb[k];
    const float cc = cb[8 + k];
    const float Bm = cb[16 + k];
    const float sE = cb[24];
    const float nup = cb[25];
    // Coefs live in the same buffer this wave writes; make sure the loads have
    // landed before any store of this wave can issue.
    asm volatile("s_waitcnt vmcnt(0)" ::: "memory");

    const float* eb = e + (size_t)wid * NT;
    const float* edb = ed + (size_t)wid * NT;
    float* xb = xi_out + (size_t)wid * (NT * 8);
    float* sb = stress + (size_t)wid * NT;

    float xs = 0.f;   // running xi_k (identical across the 8 j-groups)
    for (int t0 = 0; t0 < NT; t0 += 8) {
        const float4 u0 = *(const float4*)(eb + t0);
        const float4 u1 = *(const float4*)(eb + t0 + 4);
        const float p = edb[t0 + j];
        const float uu[8] = {u0.x, u0.y, u0.z, u0.w, u1.x, u1.y, u1.z, u1.w};
        float xi_j = 0.f, u_j = 0.f;
        #pragma unroll
        for (int s = 0; s < 8; ++s) {
            if (s == j) { xi_j = xs; u_j = uu[s]; }
            xs = fmaf(a, xs, cc * uu[s]);
        }
        xb[t0 * 8 + lane] = xi_j;                       // coalesced 256B/wave
        float contrib = Bm * (u_j - xi_j);
        contrib += __shfl_xor(contrib, 1);
        contrib += __shfl_xor(contrib, 2);
        contrib += __shfl_xor(contrib, 4);
        if (k == 0) sb[t0 + j] = fmaf(sE, u_j, contrib + nup * p);
    }
}

extern "C" void kernel_launch(void* const* d_in, const int* in_sizes, int n_in,
                              void* d_out, int out_size, void* d_ws, size_t ws_size,
                              hipStream_t stream) {
    const float* e   = (const float*)d_in[0];
    const float* ed  = (const float*)d_in[1];
    const float* E   = (const float*)d_in[2];
    const float* nu  = (const float*)d_in[3];
    const float* Bw1 = (const float*)d_in[4];
    const float* Bb1 = (const float*)d_in[5];
    const float* Bw2 = (const float*)d_in[6];
    const float* Bb2 = (const float*)d_in[7];
    const float* bw1 = (const float*)d_in[8];
    const float* bb1 = (const float*)d_in[9];
    const float* bw2 = (const float*)d_in[10];
    const float* bb2 = (const float*)d_in[11];

    float* out = (float*)d_out;
    float* stress = out;                       // [B*T]
    float* xi = out + (size_t)NB * NT;         // [B*T*8]

    enc_kernel<<<256, 256, 0, stream>>>(E, nu, Bw1, Bb1, Bw2, Bb2,
                                        bw1, bb1, bw2, bb2, xi);
    time_kernel<<<2048, 256, 0, stream>>>(e, ed, xi, stress, xi);
}

// Round 2
// 249.230 us; speedup vs baseline: 1.0830x; 1.0830x over previous
//
#include <hip/hip_runtime.h>
#include <hip/hip_bf16.h>

#define FEATN 501
#define NB 8192
#define NT 512
#define DTC 0.01f
#define NSTEP 32            // K = 1002 padded to 1024, 32 steps of 32
#define STRIDE 40           // LDS row stride in bf16 elems (80 B) - bank-friendly, 16B-aligned

typedef __attribute__((ext_vector_type(8))) short short8;
typedef __attribute__((ext_vector_type(4))) short short4v;
typedef __attribute__((ext_vector_type(4))) float f32x4;

__device__ __forceinline__ float softplus_f(float x) {
    return fmaxf(x, 0.f) + log1pf(expf(-fabsf(x)));
}
__device__ __forceinline__ short f2bf(float x) {
    __hip_bfloat16 h = __float2bfloat16(x);   // RNE
    return *reinterpret_cast<short*>(&h);
}

// ---------------- Encoder kernel (MFMA) ----------------
// grid 256, block 256 (4 waves). Each block: 32 batches x 128 hidden (both MLPs).
// C[b,h] = sum_k m[b,k] * W[k,h]  via  D = A*B with A = W^T tile (16h x 32k),
// B = m^T tile (32k x 16b).  D: row=h=(lane>>4)*4+reg, col=b=lane&15.
__global__ __launch_bounds__(256) void enc_kernel(
    const float* __restrict__ E, const float* __restrict__ nu,
    const float* __restrict__ Bw1, const float* __restrict__ Bb1,
    const float* __restrict__ Bw2, const float* __restrict__ Bb2,
    const float* __restrict__ bw1, const float* __restrict__ bb1,
    const float* __restrict__ bw2, const float* __restrict__ bb2,
    float* coef) {
    __shared__ short Wt[2][128 * STRIDE];   // [buf][h*STRIDE + k]  (W transposed, bf16)
    __shared__ short Mt[2][32 * STRIDE];    // [buf][b*STRIDE + k]  (m rows, bf16)
    __shared__ float hid[128][33];          // activated hidden [h][b]
    __shared__ float nups[32], Eps[32];

    const int tid = threadIdx.x;
    const int blk = blockIdx.x;
    const int wv = tid >> 6, lane = tid & 63;

    // ---- phase 0: harmonic-mean reductions (8 batches per wave) ----
    for (int r = 0; r < 8; ++r) {
        const int bl = wv * 8 + r;
        const size_t base = (size_t)(blk * 32 + bl) * FEATN;
        float s1 = 0.f, s2 = 0.f;
        for (int i = lane; i < FEATN; i += 64) {
            float nv = nu[base + i];
            float Ev = E[base + i];
            float inv = 1.0f / nv;
            s1 += inv;
            s2 = fmaf(Ev, inv * inv, s2);
        }
        #pragma unroll
        for (int o = 32; o; o >>= 1) {
            s1 += __shfl_xor(s1, o);
            s2 += __shfl_xor(s2, o);
        }
        if (lane == 0) {
            float np = (float)FEATN / s1;
            nups[bl] = np;
            Eps[bl] = (s2 / (float)FEATN) * np * np;
        }
    }

    // ---- staging setup ----
    // W stage: thread t -> h = t>>1 (0..127), khalf = t&1; loads 16 k's (column of W).
    // m stage: thread t -> b = t>>3 (0..31), kq = t&7; loads 4 k's (row of m).
    const int s_hh = tid >> 1;
    const int s_kh = tid & 1;
    const float* s_Wp = (s_hh < 64) ? Bw1 : bw1;
    const int s_hcol = s_hh & 63;
    const int s_b = tid >> 3;
    const int s_kq = tid & 7;
    const size_t s_mbase = (size_t)(blk * 32 + s_b) * FEATN;

    float wreg[16];
    float mreg[4];

    auto load_stage = [&](int s) {
        const int k0 = s * 32 + s_kh * 16;
        #pragma unroll
        for (int j = 0; j < 16; ++j) {
            const int k = k0 + j;
            wreg[j] = (k < 2 * FEATN) ? s_Wp[(size_t)k * 64 + s_hcol] : 0.f;
        }
        const int i0 = s * 32 + s_kq * 4;
        if (i0 + 3 < FEATN) {
            const float4 t = *(const float4*)(E + s_mbase + i0);
            mreg[0] = t.x; mreg[1] = t.y; mreg[2] = t.z; mreg[3] = t.w;
        } else if (i0 >= FEATN && i0 + 3 < 2 * FEATN) {
            const float4 t = *(const float4*)(nu + s_mbase + i0 - FEATN);
            mreg[0] = t.x; mreg[1] = t.y; mreg[2] = t.z; mreg[3] = t.w;
        } else {
            #pragma unroll
            for (int jj = 0; jj < 4; ++jj) {
                const int i = i0 + jj;
                mreg[jj] = (i < FEATN) ? E[s_mbase + i]
                         : (i < 2 * FEATN ? nu[s_mbase + i - FEATN] : 0.f);
            }
        }
    };
    auto write_stage = [&](int buf) {
        short8 wp;
        #pragma unroll
        for (int j = 0; j < 8; ++j) wp[j] = f2bf(wreg[j]);
        *(short8*)&Wt[buf][s_hh * STRIDE + s_kh * 16] = wp;
        #pragma unroll
        for (int j = 0; j < 8; ++j) wp[j] = f2bf(wreg[8 + j]);
        *(short8*)&Wt[buf][s_hh * STRIDE + s_kh * 16 + 8] = wp;
        short4v mp;
        #pragma unroll
        for (int j = 0; j < 4; ++j) mp[j] = f2bf(mreg[j]);
        *(short4v*)&Mt[buf][s_b * STRIDE + s_kq * 4] = mp;
    };

    // ---- prologue ----
    load_stage(0);
    write_stage(0);

    // ---- K loop: 4 MFMA / wave / step, one barrier / step ----
    f32x4 acc00 = {0.f, 0.f, 0.f, 0.f}, acc01 = acc00, acc10 = acc00, acc11 = acc00;
    const int r15 = lane & 15, kg = lane >> 4;
    const int aoff0 = (wv * 32 + r15) * STRIDE + kg * 8;        // h-tile 0
    const int aoff1 = (wv * 32 + 16 + r15) * STRIDE + kg * 8;   // h-tile 1
    const int boff0 = r15 * STRIDE + kg * 8;                    // b-tile 0
    const int boff1 = (16 + r15) * STRIDE + kg * 8;             // b-tile 1

    for (int s = 0; s < NSTEP; ++s) {
        __syncthreads();                  // buf[s&1] writes visible
        const int buf = s & 1;
        if (s + 1 < NSTEP) load_stage(s + 1);   // issue global loads early (T14)
        short8 a0 = *(const short8*)&Wt[buf][aoff0];
        short8 a1 = *(const short8*)&Wt[buf][aoff1];
        short8 b0 = *(const short8*)&Mt[buf][boff0];
        short8 b1 = *(const short8*)&Mt[buf][boff1];
        acc00 = __builtin_amdgcn_mfma_f32_16x16x32_bf16(a0, b0, acc00, 0, 0, 0);
        acc01 = __builtin_amdgcn_mfma_f32_16x16x32_bf16(a0, b1, acc01, 0, 0, 0);
        acc10 = __builtin_amdgcn_mfma_f32_16x16x32_bf16(a1, b0, acc10, 0, 0, 0);
        acc11 = __builtin_amdgcn_mfma_f32_16x16x32_bf16(a1, b1, acc11, 0, 0, 0);
        if (s + 1 < NSTEP) write_stage(buf ^ 1);  // cvt+ds_write into other buffer
    }

    // ---- epilogue: bias + activation -> hid LDS ----
    __syncthreads();
    {
        #pragma unroll
        for (int ht = 0; ht < 2; ++ht) {
            #pragma unroll
            for (int r = 0; r < 4; ++r) {
                const int h = wv * 32 + ht * 16 + kg * 4 + r;
                const float bias = (h < 64) ? Bb1[h] : bb1[h - 64];
                #pragma unroll
                for (int bt = 0; bt < 2; ++bt) {
                    const int b = bt * 16 + r15;
                    float v = (ht ? (bt ? acc11[r] : acc10[r])
                                  : (bt ? acc01[r] : acc00[r])) + bias;
                    v = (h < 64) ? fmaxf(v, 0.f) : softplus_f(v);
                    hid[h][b] = v;
                }
            }
        }
    }
    __syncthreads();

    // ---- layer 2 + coefficient write ----
    {
        const int bl = tid >> 3;     // 0..31
        const int k = tid & 7;       // 0..7
        float dB = 0.f, db = 0.f;
        #pragma unroll 8
        for (int h = 0; h < 64; ++h) {
            dB = fmaf(hid[h][bl],      Bw2[h * 8 + k], dB);
            db = fmaf(hid[64 + h][bl], bw2[h * 8 + k], db);
        }
        const float Bm = dB + Bb2[k];
        float be = softplus_f(db + bb2[k]);
        float Bs = Bm;
        Bs += __shfl_xor(Bs, 1);
        Bs += __shfl_xor(Bs, 2);
        Bs += __shfl_xor(Bs, 4);
        const float a = 1.f - DTC * be * (Bm + Bs);
        const float cc = DTC * be * Bm;
        const size_t bg = (size_t)(blk * 32 + bl);
        float* cb = coef + bg * 4096;
        cb[k] = a;
        cb[8 + k] = cc;
        cb[16 + k] = Bm;
        if (k == 0) {
            cb[24] = Bs * Eps[bl];
            cb[25] = nups[bl];
        }
    }
}

// ---------------- Time-loop kernel ----------------
// grid 2048, block 256: one wave per batch. lane = j*8+k.
__global__ __launch_bounds__(256) void time_kernel(
    const float* __restrict__ e, const float* __restrict__ ed,
    const float* coef, float* stress, float* xi_out) {
    const int wid = (blockIdx.x << 2) + (threadIdx.x >> 6);   // batch
    const int lane = threadIdx.x & 63;
    const int j = lane >> 3, k = lane & 7;

    const float* cb = coef + (size_t)wid * 4096;
    const float a = cb[k];
    const float cc = cb[8 + k];
    const float Bm = cb[16 + k];
    const float sE = cb[24];
    const float nup = cb[25];
    // Coefs live in the same buffer this wave writes; ensure loads landed first.
    asm volatile("s_waitcnt vmcnt(0)" ::: "memory");

    const float* eb = e + (size_t)wid * NT;
    const float* edb = ed + (size_t)wid * NT;
    float* xb = xi_out + (size_t)wid * (NT * 8);
    float* sb = stress + (size_t)wid * NT;

    float xs = 0.f;   // running xi_k
    for (int t0 = 0; t0 < NT; t0 += 8) {
        const float4 u0 = *(const float4*)(eb + t0);
        const float4 u1 = *(const float4*)(eb + t0 + 4);
        const float p = edb[t0 + j];
        const float uu[8] = {u0.x, u0.y, u0.z, u0.w, u1.x, u1.y, u1.z, u1.w};
        float xi_j = 0.f, u_j = 0.f;
        #pragma unroll
        for (int s = 0; s < 8; ++s) {
            if (s == j) { xi_j = xs; u_j = uu[s]; }
            xs = fmaf(a, xs, cc * uu[s]);
        }
        xb[t0 * 8 + lane] = xi_j;                       // coalesced 256B/wave
        float contrib = Bm * (u_j - xi_j);
        contrib += __shfl_xor(contrib, 1);
        contrib += __shfl_xor(contrib, 2);
        contrib += __shfl_xor(contrib, 4);
        if (k == 0) sb[t0 + j] = fmaf(sE, u_j, contrib + nup * p);
    }
}

extern "C" void kernel_launch(void* const* d_in, const int* in_sizes, int n_in,
                              void* d_out, int out_size, void* d_ws, size_t ws_size,
                              hipStream_t stream) {
    const float* e   = (const float*)d_in[0];
    const float* ed  = (const float*)d_in[1];
    const float* E   = (const float*)d_in[2];
    const float* nu  = (const float*)d_in[3];
    const float* Bw1 = (const float*)d_in[4];
    const float* Bb1 = (const float*)d_in[5];
    const float* Bw2 = (const float*)d_in[6];
    const float* Bb2 = (const float*)d_in[7];
    const float* bw1 = (const float*)d_in[8];
    const float* bb1 = (const float*)d_in[9];
    const float* bw2 = (const float*)d_in[10];
    const float* bb2 = (const float*)d_in[11];

    float* out = (float*)d_out;
    float* stress = out;                       // [B*T]
    float* xi = out + (size_t)NB * NT;         // [B*T*8]

    enc_kernel<<<256, 256, 0, stream>>>(E, nu, Bw1, Bb1, Bw2, Bb2,
                                        bw1, bb1, bw2, bb2, xi);
    time_kernel<<<2048, 256, 0, stream>>>(e, ed, xi, stress, xi);
}

// Round 3
// 94.859 us; speedup vs baseline: 2.8453x; 2.6274x over previous
//
#include <hip/hip_runtime.h>
#include <hip/hip_bf16.h>

#define FEATN 501
#define KPAD 1024
#define NB 8192
#define NT 512
#define DTC 0.01f

typedef __attribute__((ext_vector_type(8))) short short8;
typedef __attribute__((ext_vector_type(4))) float f32x4;

__device__ __forceinline__ float softplus_f(float x) {
    return fmaxf(x, 0.f) + log1pf(expf(-fabsf(x)));
}
__device__ __forceinline__ ushort f2bf(float x) {
    __hip_bfloat16 h = __float2bfloat16(x);   // RNE
    return *reinterpret_cast<ushort*>(&h);
}
__device__ __forceinline__ void gl_lds16(const void* g, void* l) {
    __builtin_amdgcn_global_load_lds(
        (const __attribute__((address_space(1))) void*)g,
        (__attribute__((address_space(3))) void*)l, 16, 0, 0);
}

// ---------------- prep: harmonic stats + m -> bf16 (padded) ----------------
// grid 2048 x 256 (wave per batch, 8 waves/SIMD). Writes into batch slice of
// the xi output region: floats [0..25]=coef (later), [26]=nu', [27]=E',
// floats [512..1023] = m_bf16[1024].
__global__ __launch_bounds__(256) void prep_kernel(
    const float* __restrict__ E, const float* __restrict__ nu,
    float* __restrict__ out) {
    const int b = blockIdx.x * 4 + (threadIdx.x >> 6);
    const int lane = threadIdx.x & 63;
    const size_t base = (size_t)b * FEATN;
    float* cb = out + (size_t)NB * NT + (size_t)b * 4096;
    ushort* mb = (ushort*)(cb + 512);
    float s1 = 0.f, s2 = 0.f;
    for (int i = lane; i < FEATN; i += 64) {
        const float Ev = E[base + i];
        const float nv = nu[base + i];
        const float inv = 1.0f / nv;
        s1 += inv;
        s2 = fmaf(Ev, inv * inv, s2);
        mb[i] = f2bf(Ev);
        mb[FEATN + i] = f2bf(nv);
    }
    if (lane < KPAD - 2 * FEATN) mb[2 * FEATN + lane] = 0;   // zero pad 1002..1023
    #pragma unroll
    for (int o = 32; o; o >>= 1) { s1 += __shfl_xor(s1, o); s2 += __shfl_xor(s2, o); }
    if (lane == 0) {
        const float np = (float)FEATN / s1;
        cb[26] = np;
        cb[27] = (s2 / (float)FEATN) * np * np;
    }
}

// ---------------- wtrans: W[1002][64]x2 -> Wt[128][1024] bf16 --------------
// grid 128 x 256. Wt lives at the start of the stress region (overwritten by
// time_kernel afterwards). Rows 0..63 = Bw1 cols, 64..127 = bw1 cols.
__global__ __launch_bounds__(256) void wtrans_kernel(
    const float* __restrict__ Bw1, const float* __restrict__ bw1,
    ushort* __restrict__ Wt) {
    const int h = blockIdx.x;
    const int lane = threadIdx.x & 63;
    const int wv = threadIdx.x >> 6;
    const float* W = (h < 64) ? Bw1 : bw1;
    const int col = h & 63;
    #pragma unroll
    for (int it = 0; it < 4; ++it) {
        const int k = it * 256 + wv * 64 + lane;
        const float v = (k < 2 * FEATN) ? W[(size_t)k * 64 + col] : 0.f;
        Wt[(size_t)h * KPAD + k] = f2bf(v);
    }
}

// ---------------- enc: C[16b x 128h] MFMA GEMM, K=1024 ---------------------
// grid 512 x 256 (2 blocks/CU). All staging via global_load_lds (width 16).
// Wave wv owns h-rows [wv*32, wv*32+32). D layout: col=lane&15 (=b),
// row=(lane>>4)*4+reg (=h within 16-tile).
__global__ __launch_bounds__(256) void enc_kernel(
    const ushort* __restrict__ Wt,
    const float* __restrict__ Bb1, const float* __restrict__ bb1,
    const float* __restrict__ Bw2, const float* __restrict__ Bb2,
    const float* __restrict__ bw2, const float* __restrict__ bb2,
    float* __restrict__ out) {
    __shared__ ushort Wl[2][4096];   // [buf][h*32 + kk]  128 rows x 32 k (8 KB)
    __shared__ ushort Ml[2][512];    // [buf][b*32 + kk]   16 rows x 32 k (1 KB)
    __shared__ float hid[128][17];
    const int tid = threadIdx.x;
    const int wv = tid >> 6, lane = tid & 63;
    const int bb0 = blockIdx.x * 16;
    float* xi = out + (size_t)NB * NT;

    const int srow = lane >> 2;          // 0..15 : row within a 16-row group
    const int sslot = lane & 3;          // 16B slot within 64B row
    const ushort* mbase = (const ushort*)(xi + (size_t)(bb0 + srow) * 4096 + 512);
    const int n0 = wv * 2;               // this wave's W instruction group

    auto stage = [&](int s, int buf) {
        const int kb = s * 32;           // ushort offset within a K-row
        gl_lds16(Wt + (size_t)(n0 * 16 + srow) * KPAD + kb + sslot * 8,
                 &Wl[buf][n0 * 512]);
        gl_lds16(Wt + (size_t)(n0 * 16 + 16 + srow) * KPAD + kb + sslot * 8,
                 &Wl[buf][n0 * 512 + 512]);
        if (wv == 3) gl_lds16(mbase + kb + sslot * 8, &Ml[buf][0]);
    };

    const int r15 = lane & 15, kg = lane >> 4;
    const int aoff0 = (wv * 32 + r15) * 32 + kg * 8;
    const int aoff1 = aoff0 + 16 * 32;
    const int boff = r15 * 32 + kg * 8;

    f32x4 acc0 = {0.f, 0.f, 0.f, 0.f}, acc1 = acc0;
    stage(0, 0);
    __syncthreads();                      // drain stage(0)
    for (int s = 0; s < 32; ++s) {
        const int buf = s & 1;
        if (s + 1 < 32) stage(s + 1, buf ^ 1);   // async loads fly over compute
        short8 a0 = *(const short8*)&Wl[buf][aoff0];
        short8 a1 = *(const short8*)&Wl[buf][aoff1];
        short8 b = *(const short8*)&Ml[buf][boff];
        acc0 = __builtin_amdgcn_mfma_f32_16x16x32_bf16(a0, b, acc0, 0, 0, 0);
        acc1 = __builtin_amdgcn_mfma_f32_16x16x32_bf16(a1, b, acc1, 0, 0, 0);
        __syncthreads();                  // next tile landed; all readers done
    }

    // bias + activation -> hid
    #pragma unroll
    for (int t = 0; t < 2; ++t) {
        #pragma unroll
        for (int r = 0; r < 4; ++r) {
            const int h = wv * 32 + t * 16 + kg * 4 + r;
            const float bias = (h < 64) ? Bb1[h] : bb1[h - 64];
            float v = (t ? acc1[r] : acc0[r]) + bias;
            v = (h < 64) ? fmaxf(v, 0.f) : softplus_f(v);
            hid[h][r15] = v;
        }
    }
    __syncthreads();

    // layer 2 + coefficient write (threads 0..127: bl 0..15, k 0..7)
    if (tid < 128) {
        const int bl = tid >> 3, k = tid & 7;
        float dB = 0.f, db = 0.f;
        #pragma unroll 8
        for (int h = 0; h < 64; ++h) {
            dB = fmaf(hid[h][bl], Bw2[h * 8 + k], dB);
            db = fmaf(hid[64 + h][bl], bw2[h * 8 + k], db);
        }
        const float Bm = dB + Bb2[k];
        const float be = softplus_f(db + bb2[k]);
        float Bs = Bm;
        Bs += __shfl_xor(Bs, 1);
        Bs += __shfl_xor(Bs, 2);
        Bs += __shfl_xor(Bs, 4);
        float* cb = xi + (size_t)(bb0 + bl) * 4096;
        const float np = cb[26];
        const float Ep = cb[27];
        cb[k] = 1.f - DTC * be * (Bm + Bs);
        cb[8 + k] = DTC * be * Bm;
        cb[16 + k] = Bm;
        if (k == 0) { cb[24] = Bs * Ep; cb[25] = np; }
    }
}

// ---------------- time loop ----------------
// grid 2048 x 256: one wave per batch. lane = j*8+k.
__global__ __launch_bounds__(256) void time_kernel(
    const float* __restrict__ e, const float* __restrict__ ed,
    const float* coef, float* stress, float* xi_out) {
    const int wid = (blockIdx.x << 2) + (threadIdx.x >> 6);
    const int lane = threadIdx.x & 63;
    const int j = lane >> 3, k = lane & 7;

    const float* cb = coef + (size_t)wid * 4096;
    const float a = cb[k];
    const float cc = cb[8 + k];
    const float Bm = cb[16 + k];
    const float sE = cb[24];
    const float nup = cb[25];
    // coefs live in the buffer this wave overwrites; ensure loads landed
    asm volatile("s_waitcnt vmcnt(0)" ::: "memory");

    const float* eb = e + (size_t)wid * NT;
    const float* edb = ed + (size_t)wid * NT;
    float* xb = xi_out + (size_t)wid * (NT * 8);
    float* sb = stress + (size_t)wid * NT;

    float xs = 0.f;
    for (int t0 = 0; t0 < NT; t0 += 8) {
        const float4 u0 = *(const float4*)(eb + t0);
        const float4 u1 = *(const float4*)(eb + t0 + 4);
        const float p = edb[t0 + j];
        const float uu[8] = {u0.x, u0.y, u0.z, u0.w, u1.x, u1.y, u1.z, u1.w};
        float xi_j = 0.f, u_j = 0.f;
        #pragma unroll
        for (int s = 0; s < 8; ++s) {
            if (s == j) { xi_j = xs; u_j = uu[s]; }
            xs = fmaf(a, xs, cc * uu[s]);
        }
        xb[t0 * 8 + lane] = xi_j;
        float contrib = Bm * (u_j - xi_j);
        contrib += __shfl_xor(contrib, 1);
        contrib += __shfl_xor(contrib, 2);
        contrib += __shfl_xor(contrib, 4);
        if (k == 0) sb[t0 + j] = fmaf(sE, u_j, contrib + nup * p);
    }
}

extern "C" void kernel_launch(void* const* d_in, const int* in_sizes, int n_in,
                              void* d_out, int out_size, void* d_ws, size_t ws_size,
                              hipStream_t stream) {
    const float* e   = (const float*)d_in[0];
    const float* ed  = (const float*)d_in[1];
    const float* E   = (const float*)d_in[2];
    const float* nu  = (const float*)d_in[3];
    const float* Bw1 = (const float*)d_in[4];
    const float* Bb1 = (const float*)d_in[5];
    const float* Bw2 = (const float*)d_in[6];
    const float* Bb2 = (const float*)d_in[7];
    const float* bw1 = (const float*)d_in[8];
    const float* bb1 = (const float*)d_in[9];
    const float* bw2 = (const float*)d_in[10];
    const float* bb2 = (const float*)d_in[11];

    float* out = (float*)d_out;
    float* stress = out;                        // [B*T] floats
    float* xi = out + (size_t)NB * NT;          // [B*T*8] floats
    ushort* Wt = (ushort*)out;                  // 256 KB stash in stress region

    prep_kernel<<<2048, 256, 0, stream>>>(E, nu, out);
    wtrans_kernel<<<128, 256, 0, stream>>>(Bw1, bw1, Wt);
    enc_kernel<<<512, 256, 0, stream>>>(Wt, Bb1, bb1, Bw2, Bb2, bw2, bb2, out);
    time_kernel<<<2048, 256, 0, stream>>>(e, ed, xi, stress, xi);
}